// Round 1
// baseline (386.801 us; speedup 1.0000x reference)
//
#include <hip/hip_runtime.h>

// PWC-Net cost volume, fp32.
// B=4, C=128, H=256, W=448, max_disp=4 -> 81 shifts.
// out[b, di*9+dj, h, w] = (1/128) * sum_c feat1[b,c,h,w] * feat2[b,c,h+di-4,w+dj-4]
// (zero outside bounds).
//
// Structure: one block per (b,h). 9 waves; wave wid owns di=wid. Lane owns 8
// consecutive w pixels -> acc[9][8]. feat2 rows h-4..h+4 staged to LDS
// (zero-padded halo), double-buffered 2 channels/chunk via global_load_lds.
// feat1 read direct from global (L1 absorbs 9-wave redundancy).

#define GLAS(p) ((const __attribute__((address_space(1))) unsigned int*)(p))
#define LDAS(p) ((__attribute__((address_space(3))) unsigned int*)(p))

__global__ __launch_bounds__(576) void cost_volume_kernel(
    const float* __restrict__ feat1,
    const float* __restrict__ feat2,
    float* __restrict__ out)
{
    constexpr int C = 128, H = 256, W = 448;
    constexpr int CH = 2;            // channels per LDS chunk
    constexpr int NCHUNK = C / CH;   // 64
    constexpr int ROWW = 456;        // cols -4..451 (zero halo of 4 each side)

    __shared__ float f2s[2][CH][9][ROWW];   // 65,664 B

    const int tid  = threadIdx.x;
    const int wid  = tid >> 6;   // 0..8 == di
    const int lane = tid & 63;

    // XCD-contiguous h mapping (1024 % 8 == 0 -> bijective)
    const int lin = (blockIdx.x & 7) * (int)(gridDim.x >> 3) + (blockIdx.x >> 3);
    const int b = lin >> 8;      // / 256
    const int h = lin & 255;     // % 256

    // Pre-zero LDS once: col halo + out-of-range rows stay zero forever.
    for (int i = tid; i < 2 * CH * 9 * ROWW; i += 576) ((float*)f2s)[i] = 0.0f;
    __syncthreads();

    // Lane's pixel base (8 px per lane); lanes 56..63 are clamped + store-masked.
    const int px0 = (lane < 56) ? (lane << 3) : 440;

    float acc[9][8];
#pragma unroll
    for (int j = 0; j < 9; ++j)
#pragma unroll
        for (int p = 0; p < 8; ++p) acc[j][p] = 0.0f;

    const size_t bCHW  = (size_t)b * C * H * W;
    const size_t f1row = bCHW + (size_t)h * W;

    // Stage chunk t (CH channels) into buffer buf.
    // 36 wave-load slots: slot = cl*18 + r*2 + half; each of 9 waves takes 4.
    auto stage = [&](int t, int buf) {
        const int c0 = t * CH;
#pragma unroll
        for (int k = 0; k < 4; ++k) {
            const int slot = wid + 9 * k;          // 0..35
            const int cl   = slot / 18;
            const int rem  = slot % 18;
            const int r    = rem >> 1;             // 0..8
            const int half = rem & 1;              // 0: cols 0..255, 1: cols 192..447
            const int rsrc = h + r - 4;
            if (rsrc >= 0 && rsrc < H) {
                const float* src = feat2 + bCHW
                                 + ((size_t)(c0 + cl) * H + rsrc) * W
                                 + half * 192 + lane * 4;
                float* dst = &f2s[buf][cl][r][4 + half * 192];
                __builtin_amdgcn_global_load_lds(GLAS(src), LDAS(dst), 16, 0, 0);
            }
        }
    };

    auto compute = [&](int t, int buf) {
        const int c0 = t * CH;
#pragma unroll
        for (int cl = 0; cl < CH; ++cl) {
            const float* f1p = feat1 + f1row + (size_t)(c0 + cl) * (H * W) + px0;
            const float4 a0 = *(const float4*)(f1p);
            const float4 a1 = *(const float4*)(f1p + 4);
            const float* wr = &f2s[buf][cl][wid][px0];   // window cols px0-4 .. px0+11
            const float4 w0 = *(const float4*)(wr);
            const float4 w1 = *(const float4*)(wr + 4);
            const float4 w2 = *(const float4*)(wr + 8);
            const float4 w3 = *(const float4*)(wr + 12);
            const float a[8]  = {a0.x, a0.y, a0.z, a0.w, a1.x, a1.y, a1.z, a1.w};
            const float w[16] = {w0.x, w0.y, w0.z, w0.w, w1.x, w1.y, w1.z, w1.w,
                                 w2.x, w2.y, w2.z, w2.w, w3.x, w3.y, w3.z, w3.w};
#pragma unroll
            for (int dj = 0; dj < 9; ++dj)
#pragma unroll
                for (int p = 0; p < 8; ++p)
                    acc[dj][p] = fmaf(a[p], w[dj + p], acc[dj][p]);
        }
    };

    stage(0, 0);
    __syncthreads();
    for (int t = 0; t < NCHUNK; ++t) {
        const int buf = t & 1;
        if (t + 1 < NCHUNK) stage(t + 1, buf ^ 1);
        compute(t, buf);
        __syncthreads();
    }

    // Epilogue: out[b, wid*9+dj, h, px0..px0+7], mean = *2^-7 (exact).
    if (lane < 56) {
        const float scale = 1.0f / 128.0f;
        float* obase = out + (((size_t)(b * 81 + wid * 9) * H + h) * W) + px0;
#pragma unroll
        for (int dj = 0; dj < 9; ++dj) {
            float4 o0, o1;
            o0.x = acc[dj][0] * scale; o0.y = acc[dj][1] * scale;
            o0.z = acc[dj][2] * scale; o0.w = acc[dj][3] * scale;
            o1.x = acc[dj][4] * scale; o1.y = acc[dj][5] * scale;
            o1.z = acc[dj][6] * scale; o1.w = acc[dj][7] * scale;
            float* op = obase + (size_t)dj * (H * W);
            *(float4*)(op)     = o0;
            *(float4*)(op + 4) = o1;
        }
    }
}

extern "C" void kernel_launch(void* const* d_in, const int* in_sizes, int n_in,
                              void* d_out, int out_size, void* d_ws, size_t ws_size,
                              hipStream_t stream) {
    const float* feat1 = (const float*)d_in[0];
    const float* feat2 = (const float*)d_in[1];
    float* out = (float*)d_out;
    dim3 grid(1024);
    dim3 block(576);
    cost_volume_kernel<<<grid, block, 0, stream>>>(feat1, feat2, out);
}

// Round 2
// 379.223 us; speedup vs baseline: 1.0200x; 1.0200x over previous
//
#include <hip/hip_runtime.h>

// PWC-Net cost volume, fp32. B=4, C=128, H=256, W=448, 81 shifts.
// out[b, di*9+dj, h, w] = (1/128) * sum_c feat1[b,c,h,w] * feat2[b,c,h+di-4,w+dj-4]
//
// One block per (b,h); 512 threads (8 waves). Lane item = (di, 8-px group):
// it = tid -> di = it/56, px0 = (it%56)*8  (504 real items, lanes 504..511 masked).
// feat2 rows h-4..h+4 staged in LDS, 1 channel/chunk, double-buffered via
// global_load_lds(16B). Rows are 128 16B-atoms, XOR-swizzled p = a ^ ((a>>3)&7)
// applied on the GLOBAL source address (LDS dest linear) and on read offsets
// -> window ds_read_b128 drops 4-way -> 2-way bank aliasing. Halo/pad atoms
// and out-of-range rows source from 256 zeroed bytes of d_ws.

#define GLAS(p) ((const __attribute__((address_space(1))) unsigned int*)(p))
#define LDAS(p) ((__attribute__((address_space(3))) unsigned int*)(p))

__global__ __launch_bounds__(512, 4) void cost_volume_kernel(
    const float* __restrict__ feat1,
    const float* __restrict__ feat2,
    const float* __restrict__ zws,
    float* __restrict__ out)
{
    constexpr int C = 128, H = 256, W = 448;
    constexpr int ROWB = 2048;        // bytes per LDS row (128 atoms of 16B)
    constexpr int BUFB = 9 * ROWB;    // 18432 B per buffer
    constexpr size_t HW = (size_t)H * W;

    __shared__ char f2s[2 * BUFB];    // 36864 B

    const int tid  = threadIdx.x;
    const int wid  = tid >> 6;
    const int lane = tid & 63;

    // XCD-contiguous (b,h) mapping (1024 % 8 == 0 -> bijective)
    const int lin = (blockIdx.x & 7) * ((int)gridDim.x >> 3) + (blockIdx.x >> 3);
    const int b = lin >> 8;
    const int h = lin & 255;

    const int it  = (tid < 504) ? tid : 503;
    const int di  = it / 56;
    const int m   = it - di * 56;
    const int px0 = m << 3;

    // ---- staging descriptors: 18 wave-issues (9 rows x 2 half-rows of 64 atoms).
    // Wave wid takes issues j = wid, wid+8, wid+16(<18). Lane lane writes physical
    // atom p = cc*64 + lane; its logical atom a = p ^ ((p>>3)&7) (involution, and
    // (p>>3)&7 == (lane>>3)&7 since +64 = +8 groups). Real data: a in [1,112]
    // (cols 4a-4 .. 4a-1, left halo = atom 0, right pad >= 113).
    const int lx = lane ^ ((lane >> 3) & 7);
    const float* sp[3];
    int sstep[3];
    int sdst[3];
#pragma unroll
    for (int k = 0; k < 3; ++k) {
        const int j = wid + 8 * k;
        if (j < 18) {
            const int r    = j >> 1;
            const int cc   = j & 1;
            const int a    = cc * 64 + lx;
            const int rsrc = h + r - 4;
            const bool ok  = (a >= 1) && (a <= 112) && (rsrc >= 0) && (rsrc < H);
            sp[k]    = ok ? (feat2 + ((size_t)b * C * H + rsrc) * W + (size_t)(a - 1) * 4)
                          : zws;
            sstep[k] = ok ? (int)HW : 0;
            sdst[k]  = r * ROWB + cc * 1024;
        }
    }

    // ---- window read offsets: 4 atoms a = 2m..2m+3 (cols px0-4 .. px0+11),
    // read at swizzled position within row di.
    int lofs[4];
#pragma unroll
    for (int k = 0; k < 4; ++k) {
        const int a = 2 * m + k;
        lofs[k] = di * ROWB + (a ^ ((a >> 3) & 7)) * 16;
    }

    const float* f1p = feat1 + ((size_t)b * C * H + (size_t)h) * W + px0;

    float acc[9][8];
#pragma unroll
    for (int j = 0; j < 9; ++j)
#pragma unroll
        for (int p = 0; p < 8; ++p) acc[j][p] = 0.0f;

    auto stage = [&](int buf) {
#pragma unroll
        for (int k = 0; k < 3; ++k) {
            if (wid + 8 * k < 18) {
                __builtin_amdgcn_global_load_lds(GLAS(sp[k]),
                                                 LDAS(f2s + buf * BUFB + sdst[k]),
                                                 16, 0, 0);
                sp[k] += sstep[k];
            }
        }
    };

    stage(0);
    __syncthreads();

    for (int t = 0; t < C; ++t) {
        const int buf = t & 1;
        if (t + 1 < C) stage(buf ^ 1);

        const float4 a0 = *(const float4*)(f1p);
        const float4 a1 = *(const float4*)(f1p + 4);
        f1p += HW;
        const char* lb = f2s + buf * BUFB;
        const float4 w0 = *(const float4*)(lb + lofs[0]);
        const float4 w1 = *(const float4*)(lb + lofs[1]);
        const float4 w2 = *(const float4*)(lb + lofs[2]);
        const float4 w3 = *(const float4*)(lb + lofs[3]);

        const float a[8]  = {a0.x, a0.y, a0.z, a0.w, a1.x, a1.y, a1.z, a1.w};
        const float w[16] = {w0.x, w0.y, w0.z, w0.w, w1.x, w1.y, w1.z, w1.w,
                             w2.x, w2.y, w2.z, w2.w, w3.x, w3.y, w3.z, w3.w};
#pragma unroll
        for (int dj = 0; dj < 9; ++dj)
#pragma unroll
            for (int p = 0; p < 8; ++p)
                acc[dj][p] = fmaf(a[p], w[dj + p], acc[dj][p]);

        __syncthreads();
    }

    if (tid < 504) {
        const float s = 1.0f / 128.0f;
        float* ob = out + (((size_t)(b * 81 + di * 9)) * H + h) * W + px0;
#pragma unroll
        for (int dj = 0; dj < 9; ++dj) {
            float4 o0, o1;
            o0.x = acc[dj][0] * s; o0.y = acc[dj][1] * s;
            o0.z = acc[dj][2] * s; o0.w = acc[dj][3] * s;
            o1.x = acc[dj][4] * s; o1.y = acc[dj][5] * s;
            o1.z = acc[dj][6] * s; o1.w = acc[dj][7] * s;
            float* op = ob + (size_t)dj * HW;
            *(float4*)(op)     = o0;
            *(float4*)(op + 4) = o1;
        }
    }
}

extern "C" void kernel_launch(void* const* d_in, const int* in_sizes, int n_in,
                              void* d_out, int out_size, void* d_ws, size_t ws_size,
                              hipStream_t stream) {
    const float* feat1 = (const float*)d_in[0];
    const float* feat2 = (const float*)d_in[1];
    float* out = (float*)d_out;
    // 256 zeroed bytes used as the source for halo/pad/out-of-range staging.
    hipMemsetAsync(d_ws, 0, 256, stream);
    cost_volume_kernel<<<dim3(1024), dim3(512), 0, stream>>>(
        feat1, feat2, (const float*)d_ws, out);
}